// Round 7
// baseline (84.275 us; speedup 1.0000x reference)
//
#include <hip/hip_runtime.h>

#define TPB 256

typedef __attribute__((ext_vector_type(8))) short short8;
typedef __attribute__((ext_vector_type(4))) float f32x4;

__device__ __forceinline__ unsigned f2bf_pk(float a, float b) {
  return ((__float_as_uint(a) + 0x8000u) >> 16) | ((__float_as_uint(b) + 0x8000u) & 0xffff0000u);
}
__device__ __forceinline__ float bflo(unsigned v) { return __uint_as_float(v << 16); }
__device__ __forceinline__ float bfhi(unsigned v) { return __uint_as_float(v & 0xffff0000u); }

// ---- prep: permuted bf16 A-fragment table (row permute makes each lane's
// 18x4 accumulator exactly 8 cin x 9 k for one pixel) ----------------------
__global__ void prep_kernel(const float* __restrict__ Wp, unsigned* __restrict__ Wq) {
  int idx = blockIdx.x * blockDim.x + threadIdx.x;  // 147456 u32
  if (idx >= 32 * 18 * 64 * 4) return;
  int j2   = idx & 3;
  int lane = (idx >> 2) & 63;
  int rt   = (idx >> 8) % 18;
  int o    = (idx >> 8) / 18;
  int m16 = lane & 15, kq = lane >> 4;
  int row = o * 288 + (m16 >> 2) * 72 + rt * 4 + (m16 & 3);
  const float* src = Wp + row * 32 + kq * 8 + j2 * 2;
  Wq[idx] = f2bf_pk(src[0], src[1]);
}

// ---- main: block = 64 px (one row) x 4 couts, processed as 2 pairs with
// 2-way ILP through the whole norm phase (the serial chain halves).
// x tile is px-major in LDS so patch taps are b128 reads shared by the pair.
template <bool USE_WQ>
__global__ __launch_bounds__(TPB, 2) void dppc7_kernel(
    const float* __restrict__ x, const float* __restrict__ Wp,
    const float* __restrict__ bp, const unsigned* __restrict__ Wq,
    float* __restrict__ out) {
  // [r 0..2][ww 0..65][c 0..31 pad40], bf16; stride 40 shorts = 80 B (16B aligned)
  __shared__ __align__(16) unsigned short xrow2[3 * 66 * 40];
  __shared__ __align__(16) float bp_s[4 * 288];
  __shared__ __align__(16) float Wb_s[4 * 32];
  __shared__ float bias4[4];

  const int tid = threadIdx.x;
  const int bid = blockIdx.x;
  const int og  = bid & 7;      // couts og*4 .. og*4+3
  const int t   = bid >> 3;
  const int b   = t >> 6;
  const int h   = t & 63;

  // prelude: side-halo zero words (disjoint from interior) + interior stage
  for (int i = tid; i < 120; i += TPB) {      // 6 (r,ww-halo) slots x 20 words
    int p = i / 20, w = i % 20;
    ((unsigned*)xrow2)[(((p >> 1) * 66 + ((p & 1) ? 65 : 0)) * 20) + w] = 0;
  }
  for (int i = tid; i < 1536; i += TPB) {     // r(3) x c4(8) x px(64)
    int px_ = i & 63, c4 = (i >> 6) & 7, r = i >> 9;
    int hh = h - 1 + r;
    unsigned w0 = 0, w1 = 0;
    if ((unsigned)hh < 64u) {
      const float* xp = x + ((b * 32 + c4 * 4) * 64 + hh) * 64 + px_;
      float f0 = xp[0], f1 = xp[4096], f2 = xp[8192], f3 = xp[12288];
      w0 = f2bf_pk(f0, f1);
      w1 = f2bf_pk(f2, f3);
    }
    uint2* dst = (uint2*)&xrow2[(r * 66 + 1 + px_) * 40 + c4 * 4];
    *dst = make_uint2(w0, w1);
  }
  for (int i = tid; i < 1152; i += TPB) bp_s[i] = bp[og * 1152 + i];
  if (tid < 128) Wb_s[tid] = Wp[(9216 + og * 4 + (tid >> 5)) * 32 + (tid & 31)];
  if (tid < 4) bias4[tid] = bp[9216 + og * 4 + tid];
  __syncthreads();

  const int lane = tid & 63;
  const int wv   = tid >> 6;
  const int m16  = lane & 15, kq = lane >> 4;
  const int px   = wv * 16 + m16;

  // persistent B fragment: B[k=cin=kq*8+j][n=px=m16] -> one b128
  const short8 bfrag = *(const short8*)&xrow2[(66 + 1 + px) * 40 + kq * 8];

#pragma unroll 1
  for (int pp = 0; pp < 2; ++pp) {
    const int obase = og * 4 + pp * 2;

    // phase 1: 36 MFMAs (2 couts), predictor bias folded into C-operand.
    // lane holds pred fp32 for idx=c8*9+k (cin=kq*8+c8) at px: acc[o2][idx>>2][idx&3]
    f32x4 acc[2][18];
    if (USE_WQ) {
      const short8* wq0 = (const short8*)Wq + (obase * 18) * 64 + lane;
#pragma unroll
      for (int o2 = 0; o2 < 2; ++o2)
#pragma unroll
        for (int rt = 0; rt < 18; ++rt) {
          const f32x4 bb = *(const f32x4*)&bp_s[(pp * 2 + o2) * 288 + kq * 72 + rt * 4];
          acc[o2][rt] = __builtin_amdgcn_mfma_f32_16x16x32_bf16(
              wq0[(o2 * 18 + rt) * 64], bfrag, bb, 0, 0, 0);
        }
    } else {
#pragma unroll
      for (int o2 = 0; o2 < 2; ++o2) {
        const float* ab = Wp + ((obase + o2) * 288 + (m16 >> 2) * 72 + (m16 & 3)) * 32 + kq * 8;
#pragma unroll
        for (int rt = 0; rt < 18; ++rt) {
          const float* ap = ab + rt * 4 * 32;
          float4 a0 = *(const float4*)ap;
          float4 a1 = *(const float4*)(ap + 4);
          union { short8 v; unsigned u[4]; } af;
          af.u[0] = f2bf_pk(a0.x, a0.y);
          af.u[1] = f2bf_pk(a0.z, a0.w);
          af.u[2] = f2bf_pk(a1.x, a1.y);
          af.u[3] = f2bf_pk(a1.z, a1.w);
          const f32x4 bb = *(const f32x4*)&bp_s[(pp * 2 + o2) * 288 + kq * 72 + rt * 4];
          acc[o2][rt] = __builtin_amdgcn_mfma_f32_16x16x32_bf16(af.v, bfrag, bb, 0, 0, 0);
        }
      }
    }

    // cin-norm denominators: local partials + butterflies across kq.
    // 18 independent shuffle chains (2 couts x 9 taps) co-issue.
    float rinv[2][9];
#pragma unroll
    for (int o2 = 0; o2 < 2; ++o2) {
#pragma unroll
      for (int kk = 0; kk < 9; ++kk) rinv[o2][kk] = 0.f;
#pragma unroll
      for (int c8 = 0; c8 < 8; ++c8)
#pragma unroll
        for (int kk = 0; kk < 9; ++kk) {
          const int idx = c8 * 9 + kk;
          const float v = acc[o2][idx >> 2][idx & 3];
          rinv[o2][kk] += v * v;
        }
    }
#pragma unroll
    for (int o2 = 0; o2 < 2; ++o2)
#pragma unroll
      for (int kk = 0; kk < 9; ++kk) {
        float s = rinv[o2][kk];
        s += __shfl_xor(s, 16);
        s += __shfl_xor(s, 32);
        rinv[o2][kk] = rsqrtf(fmaxf(s, 1e-24f));  // == 1/max(sqrt(s),1e-12)
      }

    // pass B: per tap k, one b128 patch read shared by both couts;
    // s2/dot accumulated per (o2, c8); r2 applied in the epilogue.
    float s2[2][8], dot[2][8];
#pragma unroll
    for (int o2 = 0; o2 < 2; ++o2)
#pragma unroll
      for (int c8 = 0; c8 < 8; ++c8) { s2[o2][c8] = 0.f; dot[o2][c8] = 0.f; }
#pragma unroll
    for (int kk = 0; kk < 9; ++kk) {
      const int kh = kk / 3, kw = kk - kh * 3;
      const uint4 tp = *(const uint4*)&xrow2[(kh * 66 + kw + px) * 40 + kq * 8];
#pragma unroll
      for (int o2 = 0; o2 < 2; ++o2) {
        const float rv = rinv[o2][kk];
#pragma unroll
        for (int c8 = 0; c8 < 8; ++c8) {
          const int idx = c8 * 9 + kk;
          const float tv = acc[o2][idx >> 2][idx & 3] * rv;
          s2[o2][c8] += tv * tv;
          const unsigned wd = ((const unsigned*)&tp)[c8 >> 1];
          const float pv = (c8 & 1) ? bfhi(wd) : bflo(wd);
          dot[o2][c8] += tv * pv;
        }
      }
    }

    // epilogue: combine per-c8, add dyn-bias partials, butterfly, store.
    const uint4 tc = *(const uint4*)&xrow2[(66 + 1 + px) * 40 + kq * 8];  // center tap
#pragma unroll
    for (int o2 = 0; o2 < 2; ++o2) {
      float oacc = 0.f;
#pragma unroll
      for (int c8 = 0; c8 < 8; ++c8) {
        oacc += rsqrtf(fmaxf(s2[o2][c8], 1e-24f)) * dot[o2][c8];
        const unsigned wd = ((const unsigned*)&tc)[c8 >> 1];
        const float xc = (c8 & 1) ? bfhi(wd) : bflo(wd);
        oacc += Wb_s[(pp * 2 + o2) * 32 + kq * 8 + c8] * xc;
      }
      oacc += __shfl_xor(oacc, 16);
      oacc += __shfl_xor(oacc, 32);
      if (kq == 0)
        out[((b * 32 + obase + o2) * 64 + h) * 64 + px] = oacc + bias4[pp * 2 + o2];
    }
  }
}

extern "C" void kernel_launch(void* const* d_in, const int* in_sizes, int n_in,
                              void* d_out, int out_size, void* d_ws, size_t ws_size,
                              hipStream_t stream) {
  const float* x  = (const float*)d_in[0];
  const float* Wp = (const float*)d_in[1];
  const float* bp = (const float*)d_in[2];
  float* out = (float*)d_out;
  const size_t wq_bytes = (size_t)32 * 18 * 64 * 8 * 2;  // 589824
  if (ws_size >= wq_bytes) {
    prep_kernel<<<576, 256, 0, stream>>>(Wp, (unsigned*)d_ws);
    dppc7_kernel<true><<<1024, TPB, 0, stream>>>(x, Wp, bp, (const unsigned*)d_ws, out);
  } else {
    dppc7_kernel<false><<<1024, TPB, 0, stream>>>(x, Wp, bp, nullptr, out);
  }
}

// Round 8
// 82.762 us; speedup vs baseline: 1.0183x; 1.0183x over previous
//
#include <hip/hip_runtime.h>

#define TPB 256

typedef __attribute__((ext_vector_type(8))) short short8;
typedef __attribute__((ext_vector_type(4))) float f32x4;

__device__ __forceinline__ unsigned f2bf_pk(float a, float b) {
  return ((__float_as_uint(a) + 0x8000u) >> 16) | ((__float_as_uint(b) + 0x8000u) & 0xffff0000u);
}
__device__ __forceinline__ float bflo(unsigned v) { return __uint_as_float(v << 16); }
__device__ __forceinline__ float bfhi(unsigned v) { return __uint_as_float(v & 0xffff0000u); }

// async global->LDS DMA, 16 B per lane (wave-uniform LDS base + lane*16)
__device__ __forceinline__ void dma16(const void* g, void* l) {
  __builtin_amdgcn_global_load_lds(
      (const __attribute__((address_space(1))) unsigned*)g,
      (__attribute__((address_space(3))) unsigned*)l, 16, 0, 0);
}

// ---- prep: permuted bf16 A-fragment table (row permute makes each lane's
// 18x4 accumulator exactly 8 cin x 9 k for one pixel) ----------------------
__global__ void prep_kernel(const float* __restrict__ Wp, unsigned* __restrict__ Wq) {
  int idx = blockIdx.x * blockDim.x + threadIdx.x;  // 147456 u32
  if (idx >= 32 * 18 * 64 * 4) return;
  int j2   = idx & 3;
  int lane = (idx >> 2) & 63;
  int rt   = (idx >> 8) % 18;
  int o    = (idx >> 8) / 18;
  int m16 = lane & 15, kq = lane >> 4;
  int row = o * 288 + (m16 >> 2) * 72 + rt * 4 + (m16 & 3);
  const float* src = Wp + row * 32 + kq * 8 + j2 * 2;
  Wq[idx] = f2bf_pk(src[0], src[1]);
}

// ---- main: block = 64 px (one row) x 4 couts. A-fragments stream through a
// double-buffered LDS region via async global_load_lds (DMA for o+1 issued
// before computing o, so L2 latency hides under the norm phase). One barrier
// per o; all norm math stays register-resident.
template <bool USE_WQ>
__global__ __launch_bounds__(TPB, 2) void dppc8_kernel(
    const float* __restrict__ x, const float* __restrict__ Wp,
    const float* __restrict__ bp, const unsigned* __restrict__ Wq,
    float* __restrict__ out) {
  // [r 0..2][ww 0..65][c 0..31 pad40], bf16; stride 40 shorts = 80 B
  __shared__ __align__(16) unsigned short xrow2[3 * 66 * 40];   // 15840 B
  __shared__ __align__(16) char wqbuf[2][18432];                // 36864 B
  __shared__ __align__(16) float bp_s[4 * 288];                 // 4608 B
  __shared__ __align__(16) float Wb_s[4 * 32];
  __shared__ float bias4[4];

  const int tid = threadIdx.x;
  const int bid = blockIdx.x;
  const int og  = bid & 7;      // couts og*4 .. og*4+3
  const int t   = bid >> 3;
  const int b   = t >> 6;
  const int h   = t & 63;

  const char* wq_g = (const char*)Wq + (size_t)(og * 4) * 18432;

  // kick off DMA for o=0 immediately; it completes under the prelude
  if (USE_WQ) {
    for (int c = tid; c < 1152; c += TPB)
      dma16(wq_g + c * 16, wqbuf[0] + c * 16);
  }

  // prelude: side-halo zero words (disjoint from interior) + interior stage
  for (int i = tid; i < 120; i += TPB) {      // 6 (r,ww-halo) slots x 20 words
    int p = i / 20, w = i % 20;
    ((unsigned*)xrow2)[(((p >> 1) * 66 + ((p & 1) ? 65 : 0)) * 20) + w] = 0;
  }
  for (int i = tid; i < 1536; i += TPB) {     // r(3) x c4(8) x px(64)
    int px_ = i & 63, c4 = (i >> 6) & 7, r = i >> 9;
    int hh = h - 1 + r;
    unsigned w0 = 0, w1 = 0;
    if ((unsigned)hh < 64u) {
      const float* xp = x + ((b * 32 + c4 * 4) * 64 + hh) * 64 + px_;
      float f0 = xp[0], f1 = xp[4096], f2 = xp[8192], f3 = xp[12288];
      w0 = f2bf_pk(f0, f1);
      w1 = f2bf_pk(f2, f3);
    }
    uint2* dst = (uint2*)&xrow2[(r * 66 + 1 + px_) * 40 + c4 * 4];
    *dst = make_uint2(w0, w1);
  }
  for (int i = tid; i < 1152; i += TPB) bp_s[i] = bp[og * 1152 + i];
  if (tid < 128) Wb_s[tid] = Wp[(9216 + og * 4 + (tid >> 5)) * 32 + (tid & 31)];
  if (tid < 4) bias4[tid] = bp[9216 + og * 4 + tid];
  __syncthreads();   // drains prelude stores AND the o=0 DMA

  const int lane = tid & 63;
  const int wv   = tid >> 6;
  const int m16  = lane & 15, kq = lane >> 4;
  const int px   = wv * 16 + m16;

  // persistent B fragment: B[k=cin=kq*8+j][n=px=m16] -> one b128
  const short8 bfrag = *(const short8*)&xrow2[(66 + 1 + px) * 40 + kq * 8];

  // patch taps, pre-packed bf16 pairs: patch2[kk*4 + (c8>>1)] = cins (2c,2c+1)
  unsigned patch2[36];
#pragma unroll
  for (int kk = 0; kk < 9; ++kk) {
    const int kh = kk / 3, kw = kk - kh * 3;
    const uint4 tp = *(const uint4*)&xrow2[(kh * 66 + kw + px) * 40 + kq * 8];
    patch2[kk * 4 + 0] = tp.x;
    patch2[kk * 4 + 1] = tp.y;
    patch2[kk * 4 + 2] = tp.z;
    patch2[kk * 4 + 3] = tp.w;
  }

#pragma unroll 1
  for (int oo = 0; oo < 4; ++oo) {
    const int o = og * 4 + oo;
    const int buf = oo & 1;

    // issue DMA for o+1 into the other buffer; rides under this o's compute
    if (USE_WQ && oo < 3) {
      const char* g = wq_g + (size_t)(oo + 1) * 18432;
      for (int c = tid; c < 1152; c += TPB)
        dma16(g + c * 16, wqbuf[buf ^ 1] + c * 16);
    }

    // phase 1: 18 MFMAs, predictor bias folded into C-operand.
    // lane holds pred fp32 for idx=c8*9+k (cin=kq*8+c8) at px: acc[idx>>2][idx&3]
    f32x4 acc[18];
    if (USE_WQ) {
#pragma unroll
      for (int rt = 0; rt < 18; ++rt) {
        const short8 a = *(const short8*)(wqbuf[buf] + (rt * 64 + lane) * 16);
        const f32x4 bb = *(const f32x4*)&bp_s[oo * 288 + kq * 72 + rt * 4];
        acc[rt] = __builtin_amdgcn_mfma_f32_16x16x32_bf16(a, bfrag, bb, 0, 0, 0);
      }
    } else {
      const float* ab = Wp + (o * 288 + (m16 >> 2) * 72 + (m16 & 3)) * 32 + kq * 8;
#pragma unroll
      for (int rt = 0; rt < 18; ++rt) {
        const float* ap = ab + rt * 4 * 32;
        float4 a0 = *(const float4*)ap;
        float4 a1 = *(const float4*)(ap + 4);
        union { short8 v; unsigned u[4]; } af;
        af.u[0] = f2bf_pk(a0.x, a0.y);
        af.u[1] = f2bf_pk(a0.z, a0.w);
        af.u[2] = f2bf_pk(a1.x, a1.y);
        af.u[3] = f2bf_pk(a1.z, a1.w);
        const f32x4 bb = *(const f32x4*)&bp_s[oo * 288 + kq * 72 + rt * 4];
        acc[rt] = __builtin_amdgcn_mfma_f32_16x16x32_bf16(af.v, bfrag, bb, 0, 0, 0);
      }
    }

    // cin-norm denominators: local partial + butterfly across kq (bits 4,5)
    float rinv[9];
#pragma unroll
    for (int kk = 0; kk < 9; ++kk) rinv[kk] = 0.f;
#pragma unroll
    for (int c8 = 0; c8 < 8; ++c8)
#pragma unroll
      for (int kk = 0; kk < 9; ++kk) {
        const int idx = c8 * 9 + kk;
        const float v = acc[idx >> 2][idx & 3];
        rinv[kk] += v * v;
      }
#pragma unroll
    for (int kk = 0; kk < 9; ++kk) {
      float s = rinv[kk];
      s += __shfl_xor(s, 16);
      s += __shfl_xor(s, 32);
      rinv[kk] = rsqrtf(fmaxf(s, 1e-24f));  // == 1/max(sqrt(s),1e-12)
    }

    // k-norm + contraction + dyn-bias partials: s2 and dot in one pass
    float oacc = 0.f;
#pragma unroll
    for (int c8 = 0; c8 < 8; ++c8) {
      float s2 = 0.f, dot = 0.f;
#pragma unroll
      for (int kk = 0; kk < 9; ++kk) {
        const int idx = c8 * 9 + kk;
        const float tv = acc[idx >> 2][idx & 3] * rinv[kk];
        s2 += tv * tv;
        const unsigned wd = patch2[kk * 4 + (c8 >> 1)];
        const float pv = (c8 & 1) ? bfhi(wd) : bflo(wd);
        dot += tv * pv;
      }
      oacc += rsqrtf(fmaxf(s2, 1e-24f)) * dot;
      const unsigned wc = patch2[16 + (c8 >> 1)];         // center tap kk=4
      const float xc = (c8 & 1) ? bfhi(wc) : bflo(wc);
      oacc += Wb_s[oo * 32 + kq * 8 + c8] * xc;
    }
    oacc += __shfl_xor(oacc, 16);
    oacc += __shfl_xor(oacc, 32);
    if (kq == 0)
      out[((b * 32 + o) * 64 + h) * 64 + px] = oacc + bias4[oo];

    // protect buffer reuse: all waves done reading wqbuf[buf] before the
    // DMA issued at iteration oo+1 overwrites it; also completes DMA(oo+1).
    if (oo < 3) __syncthreads();
  }
}

extern "C" void kernel_launch(void* const* d_in, const int* in_sizes, int n_in,
                              void* d_out, int out_size, void* d_ws, size_t ws_size,
                              hipStream_t stream) {
  const float* x  = (const float*)d_in[0];
  const float* Wp = (const float*)d_in[1];
  const float* bp = (const float*)d_in[2];
  float* out = (float*)d_out;
  const size_t wq_bytes = (size_t)32 * 18 * 64 * 8 * 2;  // 589824
  if (ws_size >= wq_bytes) {
    prep_kernel<<<576, 256, 0, stream>>>(Wp, (unsigned*)d_ws);
    dppc8_kernel<true><<<1024, TPB, 0, stream>>>(x, Wp, bp, (const unsigned*)d_ws, out);
  } else {
    dppc8_kernel<false><<<1024, TPB, 0, stream>>>(x, Wp, bp, nullptr, out);
  }
}

// Round 9
// 80.228 us; speedup vs baseline: 1.0504x; 1.0316x over previous
//
#include <hip/hip_runtime.h>

#define TPB 256

typedef __attribute__((ext_vector_type(8))) short short8;
typedef __attribute__((ext_vector_type(4))) float f32x4;

__device__ __forceinline__ unsigned f2bf_pk(float a, float b) {
  return ((__float_as_uint(a) + 0x8000u) >> 16) | ((__float_as_uint(b) + 0x8000u) & 0xffff0000u);
}
__device__ __forceinline__ float bflo(unsigned v) { return __uint_as_float(v << 16); }
__device__ __forceinline__ float bfhi(unsigned v) { return __uint_as_float(v & 0xffff0000u); }

// async global->LDS DMA, 16 B per lane (wave-uniform LDS base + lane*16)
__device__ __forceinline__ void dma16(const void* g, void* l) {
  __builtin_amdgcn_global_load_lds(
      (const __attribute__((address_space(1))) unsigned*)g,
      (__attribute__((address_space(3))) unsigned*)l, 16, 0, 0);
}

// ---- prep: permuted bf16 A-fragment table (row permute makes each lane's
// 18x4 accumulator exactly 8 cin x 9 k for one pixel) ----------------------
__global__ void prep_kernel(const float* __restrict__ Wp, unsigned* __restrict__ Wq) {
  int idx = blockIdx.x * blockDim.x + threadIdx.x;  // 147456 u32
  if (idx >= 32 * 18 * 64 * 4) return;
  int j2   = idx & 3;
  int lane = (idx >> 2) & 63;
  int rt   = (idx >> 8) % 18;
  int o    = (idx >> 8) / 18;
  int m16 = lane & 15, kq = lane >> 4;
  int row = o * 288 + (m16 >> 2) * 72 + rt * 4 + (m16 & 3);
  const float* src = Wp + row * 32 + kq * 8 + j2 * 2;
  Wq[idx] = f2bf_pk(src[0], src[1]);
}

// ---- main: 1024 blocks = exactly 4/CU resident (one generation, 16 waves/CU
// for stall hiding). LDS 39.4 KB/block; regs trimmed to fit 128/wave:
// patch taps + bfrag re-read from LDS each o, A-frags via single-buffered
// async-DMA LDS (DMA for o+1 issued post-MFMA-barrier, drained at loop end).
template <bool USE_WQ>
__global__ __launch_bounds__(TPB, 4) void dppc9_kernel(
    const float* __restrict__ x, const float* __restrict__ Wp,
    const float* __restrict__ bp, const unsigned* __restrict__ Wq,
    float* __restrict__ out) {
  // [r 0..2][ww 0..65][c 0..31 pad40], bf16; stride 40 shorts = 80 B
  __shared__ __align__(16) unsigned short xrow2[3 * 66 * 40];   // 15840 B
  __shared__ __align__(16) char wqbuf[18432];                   // 18432 B
  __shared__ __align__(16) float bp_s[4 * 288];                 // 4608 B
  __shared__ __align__(16) float Wb_s[4 * 32];                  // 512 B
  __shared__ float bias4[4];

  const int tid = threadIdx.x;
  const int bid = blockIdx.x;
  const int og  = bid & 7;      // couts og*4 .. og*4+3
  const int t   = bid >> 3;
  const int b   = t >> 6;
  const int h   = t & 63;

  const char* wq_g = (const char*)Wq + (size_t)(og * 4) * 18432;

  // kick off DMA for o=0 immediately; it completes under the prelude
  if (USE_WQ) {
    for (int c = tid; c < 1152; c += TPB)
      dma16(wq_g + c * 16, wqbuf + c * 16);
  }

  // prelude: side-halo zero words (disjoint from interior) + interior stage
  for (int i = tid; i < 120; i += TPB) {      // 6 (r,ww-halo) slots x 20 words
    int p = i / 20, w = i % 20;
    ((unsigned*)xrow2)[(((p >> 1) * 66 + ((p & 1) ? 65 : 0)) * 20) + w] = 0;
  }
  for (int i = tid; i < 1536; i += TPB) {     // r(3) x c4(8) x px(64)
    int px_ = i & 63, c4 = (i >> 6) & 7, r = i >> 9;
    int hh = h - 1 + r;
    unsigned w0 = 0, w1 = 0;
    if ((unsigned)hh < 64u) {
      const float* xp = x + ((b * 32 + c4 * 4) * 64 + hh) * 64 + px_;
      float f0 = xp[0], f1 = xp[4096], f2 = xp[8192], f3 = xp[12288];
      w0 = f2bf_pk(f0, f1);
      w1 = f2bf_pk(f2, f3);
    }
    uint2* dst = (uint2*)&xrow2[(r * 66 + 1 + px_) * 40 + c4 * 4];
    *dst = make_uint2(w0, w1);
  }
  for (int i = tid; i < 1152; i += TPB) bp_s[i] = bp[og * 1152 + i];
  if (tid < 128) Wb_s[tid] = Wp[(9216 + og * 4 + (tid >> 5)) * 32 + (tid & 31)];
  if (tid < 4) bias4[tid] = bp[9216 + og * 4 + tid];
  __syncthreads();   // drains prelude stores AND the o=0 DMA

  const int lane = tid & 63;
  const int wv   = tid >> 6;
  const int m16  = lane & 15, kq = lane >> 4;
  const int px   = wv * 16 + m16;

#pragma unroll 1
  for (int oo = 0; oo < 4; ++oo) {
    const int o = og * 4 + oo;

    // B fragment re-read each o (keeps it out of the long-lived reg set)
    const short8 bfrag = *(const short8*)&xrow2[(66 + 1 + px) * 40 + kq * 8];

    // phase 1: 18 MFMAs, predictor bias folded into C-operand.
    // lane holds pred fp32 for idx=c8*9+k (cin=kq*8+c8) at px: acc[idx>>2][idx&3]
    f32x4 acc[18];
    if (USE_WQ) {
#pragma unroll
      for (int rt = 0; rt < 18; ++rt) {
        const short8 a = *(const short8*)(wqbuf + (rt * 64 + lane) * 16);
        const f32x4 bb = *(const f32x4*)&bp_s[oo * 288 + kq * 72 + rt * 4];
        acc[rt] = __builtin_amdgcn_mfma_f32_16x16x32_bf16(a, bfrag, bb, 0, 0, 0);
      }
    } else {
      const float* ab = Wp + (o * 288 + (m16 >> 2) * 72 + (m16 & 3)) * 32 + kq * 8;
#pragma unroll
      for (int rt = 0; rt < 18; ++rt) {
        const float* ap = ab + rt * 4 * 32;
        float4 a0 = *(const float4*)ap;
        float4 a1 = *(const float4*)(ap + 4);
        union { short8 v; unsigned u[4]; } af;
        af.u[0] = f2bf_pk(a0.x, a0.y);
        af.u[1] = f2bf_pk(a0.z, a0.w);
        af.u[2] = f2bf_pk(a1.x, a1.y);
        af.u[3] = f2bf_pk(a1.z, a1.w);
        const f32x4 bb = *(const f32x4*)&bp_s[oo * 288 + kq * 72 + rt * 4];
        acc[rt] = __builtin_amdgcn_mfma_f32_16x16x32_bf16(af.v, bfrag, bb, 0, 0, 0);
      }
    }

    // single-buffer handoff: all waves done reading wqbuf, then start DMA
    // for o+1; it rides under the entire norm phase below.
    if (USE_WQ && oo < 3) {
      __syncthreads();
      const char* g = wq_g + (size_t)(oo + 1) * 18432;
      for (int c = tid; c < 1152; c += TPB)
        dma16(g + c * 16, wqbuf + c * 16);
    }

    // cin-norm denominators: local partial + butterfly across kq (bits 4,5)
    float rinv[9];
#pragma unroll
    for (int kk = 0; kk < 9; ++kk) rinv[kk] = 0.f;
#pragma unroll
    for (int c8 = 0; c8 < 8; ++c8)
#pragma unroll
      for (int kk = 0; kk < 9; ++kk) {
        const int idx = c8 * 9 + kk;
        const float v = acc[idx >> 2][idx & 3];
        rinv[kk] += v * v;
      }
#pragma unroll
    for (int kk = 0; kk < 9; ++kk) {
      float s = rinv[kk];
      s += __shfl_xor(s, 16);
      s += __shfl_xor(s, 32);
      rinv[kk] = rsqrtf(fmaxf(s, 1e-24f));  // == 1/max(sqrt(s),1e-12)
    }

    // pass B: per tap k one b128 patch read (px-major x-tile), s2/dot
    // accumulated per c8; k-norm applied in the epilogue.
    float s2[8], dot[8];
#pragma unroll
    for (int c8 = 0; c8 < 8; ++c8) { s2[c8] = 0.f; dot[c8] = 0.f; }
#pragma unroll
    for (int kk = 0; kk < 9; ++kk) {
      const int kh = kk / 3, kw = kk - kh * 3;
      const uint4 tp = *(const uint4*)&xrow2[(kh * 66 + kw + px) * 40 + kq * 8];
      const float rv = rinv[kk];
#pragma unroll
      for (int c8 = 0; c8 < 8; ++c8) {
        const int idx = c8 * 9 + kk;
        const float tv = acc[idx >> 2][idx & 3] * rv;
        s2[c8] += tv * tv;
        const unsigned wd = ((const unsigned*)&tp)[c8 >> 1];
        const float pv = (c8 & 1) ? bfhi(wd) : bflo(wd);
        dot[c8] += tv * pv;
      }
    }

    // epilogue: combine per-c8, add dyn-bias partials, butterfly, store.
    const uint4 tc = *(const uint4*)&xrow2[(66 + 1 + px) * 40 + kq * 8];  // center tap
    float oacc = 0.f;
#pragma unroll
    for (int c8 = 0; c8 < 8; ++c8) {
      oacc += rsqrtf(fmaxf(s2[c8], 1e-24f)) * dot[c8];
      const unsigned wd = ((const unsigned*)&tc)[c8 >> 1];
      const float xc = (c8 & 1) ? bfhi(wd) : bflo(wd);
      oacc += Wb_s[oo * 32 + kq * 8 + c8] * xc;
    }
    oacc += __shfl_xor(oacc, 16);
    oacc += __shfl_xor(oacc, 32);
    if (kq == 0)
      out[((b * 32 + o) * 64 + h) * 64 + px] = oacc + bias4[oo];

    // drain DMA(o+1) + make wqbuf writes visible before next MFMA phase
    if (oo < 3) __syncthreads();
  }
}

extern "C" void kernel_launch(void* const* d_in, const int* in_sizes, int n_in,
                              void* d_out, int out_size, void* d_ws, size_t ws_size,
                              hipStream_t stream) {
  const float* x  = (const float*)d_in[0];
  const float* Wp = (const float*)d_in[1];
  const float* bp = (const float*)d_in[2];
  float* out = (float*)d_out;
  const size_t wq_bytes = (size_t)32 * 18 * 64 * 8 * 2;  // 589824
  if (ws_size >= wq_bytes) {
    prep_kernel<<<576, 256, 0, stream>>>(Wp, (unsigned*)d_ws);
    dppc9_kernel<true><<<1024, TPB, 0, stream>>>(x, Wp, bp, (const unsigned*)d_ws, out);
  } else {
    dppc9_kernel<false><<<1024, TPB, 0, stream>>>(x, Wp, bp, nullptr, out);
  }
}